// Round 15
// baseline (164.193 us; speedup 1.0000x reference)
//
#include <hip/hip_runtime.h>
#include <stdint.h>

typedef unsigned long long u64;
typedef unsigned int u32;

#define BB   4
#define CC   4
#define HHH  512
#define WWW  512
#define HW   (HHH*WWW)        /* 262144 = 2^18 */
#define NIMG (BB*CC)          /* 16 */
#define NSRC 2
#define NLVL 5
#define NB   (NLVL*NIMG)      /* 80 images per src */
#define NSIMG (NSRC*NB)       /* 160 combined batch images */
#define KTOP 64
#define NBIN 4096             /* histogram bins; sizes > NBIN go to the large list (<=63) */
#define WPI  4096             /* 64-bit words per image (512 rows * 8) */
#define SLICE ((size_t)NSRC*NIMG*WPI)  /* words per level slice (131072) */
#define TROWS 32              /* tile = 32 rows x 512 cols */
#define TPX  (TROWS*WWW)      /* 16384 px per tile */
#define TWORDS (TROWS*8)      /* 256 words per tile */
#define NTILE 16              /* tiles per image */
#define NSEAM (NTILE-1)       /* 15 row-seams per image */
#define RCAP 8192             /* max roots per tile (checkerboard bound) */
#define GSP  (NTILE*RCAP)     /* gid space per image (131072) */

// ---------------- union-find over ids (any total order works: only ---------
// connectivity + sizes matter). Convergence test uses ONLY atomic return
// values; path-halving stores write valid ancestors.

__device__ __forceinline__ void unite(int* L, int a, int b) {
  bool done = false;
  do {
    { int p = L[a]; while (p != a) { int gp = L[p]; L[a] = gp; a = gp; p = L[a]; } }
    { int p = L[b]; while (p != b) { int gp = L[p]; L[b] = gp; b = gp; p = L[b]; } }
    if (a < b) {
      int old = atomicMin(&L[b], a);
      done = (old == b);
      b = old;
    } else if (b < a) {
      int old = atomicMin(&L[a], b);
      done = (old == a);
      a = old;
    } else {
      done = true;
    }
  } while (!done);
}

// run start bit (within 64-px segment) for a pixel at bit k of word w
__device__ __forceinline__ int runstart_bit(u64 w, int k) {
  u64 lowz = ~w & ((k == 0) ? 0ull : ((1ull << k) - 1));
  return lowz ? (64 - __clzll(lowz)) : 0;   // highest zero below k, +1
}

// LPT block ordering: heaviest level (base speckle lvl2) first
__device__ __forceinline__ int lvl_of_slot(int s) {
  return s == 0 ? 2 : s == 1 ? 0 : s == 2 ? 1 : s == 3 ? 3 : 4;
}

// 3x3 box morphology of one word given its 8 neighbors packed
__device__ __forceinline__ u64 morph_word(u64 c0, u64 cm, u64 cp, u64 u0, u64 um, u64 up_,
                                          u64 d0, u64 dm, u64 dp, int erode) {
  u64 v, vm, vp;
  if (erode) {
    v = u0 & c0 & d0; vm = um & cm & dm; vp = up_ & cp & dp;
    return v & ((v << 1) | (vm >> 63)) & ((v >> 1) | (vp << 63));
  } else {
    v = u0 | c0 | d0; vm = um | cm | dm; vp = up_ | cp | dp;
    return v | (v << 1) | (vm >> 63) | (v >> 1) | (vp << 63);
  }
}

// ------------- bitmaps: [lvl][src][img][WPI] u64 words, 1 bit/px -----------

__global__ void k_base_mask_bits(const float* __restrict__ pred, const int* __restrict__ tgt,
                                 u64* __restrict__ bm) {
  int i = blockIdx.x * blockDim.x + threadIdx.x;   // over BB*HW
  if (i >= BB * HW) return;
  int b  = i >> 18;
  int hw = i & (HW - 1);
  float p0 = pred[(b * CC + 0) * HW + hw];
  float p1 = pred[(b * CC + 1) * HW + hw];
  float p2 = pred[(b * CC + 2) * HW + hw];
  float p3 = pred[(b * CC + 3) * HW + hw];
  int amax = 0; float best = p0;
  if (p1 > best) { best = p1; amax = 1; }
  if (p2 > best) { best = p2; amax = 2; }
  if (p3 > best) { best = p3; amax = 3; }
  int tg = tgt[i];
  int lane = threadIdx.x & 63;
  u64* bp = bm + 2 * SLICE;                        // lvl2, src0
  u64* bt = bm + 2 * SLICE + (size_t)NIMG * WPI;   // lvl2, src1
#pragma unroll
  for (int c = 0; c < CC; ++c) {
    u64 wp = __ballot(amax == c);
    u64 wt = __ballot(tg == c);
    if (lane == 0) {
      int wi = ((b * CC + c) << 12) + (hw >> 6);
      bp[wi] = wp;
      bt[wi] = wt;
    }
  }
}

// Fused double-morphology, BOTH chains in one dispatch. LDS-tiled, 2-row
// halo; m1 rows outside the image forced to 0.
__global__ void k_morph2(u64* __restrict__ bm) {
  __shared__ u64 a[68 * 8];
  __shared__ u64 bsh[66 * 8];
  int blk = blockIdx.x;              // 512
  int erode = (blk < 256);
  int blk2 = blk & 255;
  int band = blk2 & 7;
  int imgi = blk2 >> 3;              // 0..31 (src*img within level slice)
  int r0 = band * 64;
  const u64* ip = bm + 2 * SLICE + ((size_t)imgi << 12);
  u64* o1 = bm + (erode ? 3 : 1) * SLICE + ((size_t)imgi << 12);
  u64* o2 = bm + (erode ? 4 : 0) * SLICE + ((size_t)imgi << 12);
  int t = threadIdx.x;               // 256
  for (int k = t; k < 68 * 8; k += 256) {
    int rr = r0 - 2 + (k >> 3);
    a[k] = (rr >= 0 && rr < HHH) ? ip[rr * 8 + (k & 7)] : 0;
  }
  __syncthreads();
  for (int k = t; k < 66 * 8; k += 256) {
    int j = k >> 3, wc = k & 7;
    int rr = r0 - 1 + j;
    if (rr < 0 || rr >= HHH) { bsh[k] = 0; continue; }
    int ai = (j + 1) * 8 + wc;
    bsh[k] = morph_word(a[ai], wc ? a[ai - 1] : 0, (wc < 7) ? a[ai + 1] : 0,
                        a[ai - 8], wc ? a[ai - 9] : 0, (wc < 7) ? a[ai - 7] : 0,
                        a[ai + 8], wc ? a[ai + 7] : 0, (wc < 7) ? a[ai + 9] : 0, erode);
  }
  __syncthreads();
  for (int k = t; k < 512; k += 256) {
    int j = k >> 3, wc = k & 7;
    int bi = (j + 1) * 8 + wc;
    o1[(r0 + j) * 8 + wc] = bsh[bi];
    o2[(r0 + j) * 8 + wc] =
        morph_word(bsh[bi], wc ? bsh[bi - 1] : 0, (wc < 7) ? bsh[bi + 1] : 0,
                   bsh[bi - 8], wc ? bsh[bi - 9] : 0, (wc < 7) ? bsh[bi - 7] : 0,
                   bsh[bi + 8], wc ? bsh[bi + 7] : 0, (wc < 7) ? bsh[bi + 9] : 0, erode);
  }
}

// -------- CCL phase A: per-tile UF + sizes in LDS; dense-gid outputs --------
// par encoding: low 14 bits = parent pixel idx; bits >=14 = size at roots.
// Root bitmap via BALLOT in the flatten pass (no LDS atomics); boundary-row
// roots stashed during flatten (no re-walk pass); single-wave shfl scan.

__global__ __launch_bounds__(1024) void k_ccl_tile(const u64* __restrict__ bm,
                                                   int* __restrict__ bound,
                                                   int* __restrict__ gparent,
                                                   int* __restrict__ sizes,
                                                   int* __restrict__ rootcnt) {
  __shared__ int par[TPX];          // 64 KB
  __shared__ u64 w[TWORDS];         // 2 KB
  __shared__ u64 rbm[TWORDS];       // 2 KB root bitmap (ballot-built)
  __shared__ int rcnt[256];         // inclusive per-word root counts
  __shared__ int stash[1024];       // boundary-row head roots (rows 0 / 31)
  __shared__ int anyfg;
  int t = threadIdx.x;              // 1024
  int idx = blockIdx.x;             // 2560
  int lvl = lvl_of_slot(idx >> 9);
  int rem = idx & 511;
  int src = rem >> 8;
  int img = (rem >> 4) & 15;
  int tin = rem & 15;
  int simg = src * NB + lvl * NIMG + img;   // 0..159
  int tile = simg * NTILE + tin;
  int trow0 = tin * TROWS;
  const u64* ib = bm + ((size_t)((lvl * NSRC + src) * NIMG + img) << 12);
  if (t == 0) anyfg = 0;
  stash[t] = -1;
  // fused load + serial head-init
  if (t < TWORDS) {
    u64 wd = ib[trow0 * 8 + t];
    w[t] = wd;
    if (wd) {
      anyfg = 1;                    // benign same-value race
      int segbase = t << 6;
      u64 hm = wd & ~(wd << 1);
      while (hm) {
        int k = __ffsll(hm) - 1; hm &= hm - 1;
        par[segbase + k] = segbase + k;
      }
    }
  }
  __syncthreads();
  if (!anyfg) { if (t == 0) rootcnt[tile] = 0; return; }
  int wave = t >> 6, lane = t & 63;
  // intra-tile unites: one wave per word, one lane per need-bit (LDS atomics)
  for (int i = wave; i < TWORDS; i += 16) {
    u64 r0 = w[i];
    if (!r0) continue;
    int row = i >> 3, wc = i & 7;
    int segbase = i << 6;
    u64 prev = wc ? w[i - 1] : 0;
    if (lane == 0 && (r0 & 1) && (prev >> 63))
      unite(par, segbase, segbase - 64 + runstart_bit(prev, 63));
    if (row) {
      u64 up = w[i - 8];
      u64 both = r0 & up;
      if (both) {
        u64 upprev = wc ? w[i - 9] : 0;
        u64 lsr0 = (r0 << 1) | (prev >> 63);
        u64 lsup = (up << 1) | (upprev >> 63);
        u64 need = both & ~(lsr0 & lsup);
        if ((need >> lane) & 1)
          unite(par, segbase + runstart_bit(r0, lane),
                     segbase - 512 + runstart_bit(up, lane));
      }
    }
  }
  __syncthreads();
  // flatten + size-accumulate + ballot root bitmap + boundary stash +
  // path compression. Masked walk (low 14 bits) is immune to concurrent
  // size atomicAdds (those only target final roots; addend low bits 0).
  for (int i = wave; i < TWORDS; i += 16) {
    u64 wd = w[i];
    if (!wd) { if (lane == 0) rbm[i] = 0; continue; }
    u64 hm = wd & ~(wd << 1);
    bool head = (hm >> lane) & 1;
    int p = (i << 6) + lane;
    int r = p;
    if (head) {
      int q = par[r] & 16383;
      while (q != r) { r = q; q = par[r] & 16383; }
      u64 inv = ~(wd >> lane);
      int len = inv ? (__ffsll(inv) - 1) : (64 - lane);
      atomicAdd(&par[r], len << 14);
      if (r != p) par[p] = r;       // compress (non-root high bits unused)
      if (i < 8) stash[(i << 6) + lane] = r;
      else if (i >= 248) stash[512 + ((i - 248) << 6) + lane] = r;
    }
    u64 rootm = __ballot(head && r == p);
    if (lane == 0) rbm[i] = rootm;
  }
  __syncthreads();
  // single-wave inclusive scan of per-word root counts (2 barriers not 16)
  if (t < 64) {
    int b4 = t * 4;
    int c0 = __popcll(rbm[b4]);
    int c1 = c0 + __popcll(rbm[b4 + 1]);
    int c2 = c1 + __popcll(rbm[b4 + 2]);
    int c3 = c2 + __popcll(rbm[b4 + 3]);
    int sum = c3;
    for (int o = 1; o < 64; o <<= 1) {
      int v = __shfl_up(sum, o);
      if (t >= o) sum += v;
    }
    int excl = sum - c3;
    rcnt[b4] = excl + c0;
    rcnt[b4 + 1] = excl + c1;
    rcnt[b4 + 2] = excl + c2;
    rcnt[b4 + 3] = excl + c3;
  }
  __syncthreads();
  // boundary publish from stash (no re-walk)
  {
    int r = stash[t];
    if (r >= 0) {
      int wi = r >> 6;
      u64 rbw = rbm[wi];
      int slot = rcnt[wi] - __popcll(rbw) +
                 __popcll(rbw & (((u64)1 << (r & 63)) - 1));
      bound[(size_t)tile * 1024 + t] = tin * RCAP + slot;
    }
  }
  // dense emit of sizes + gparent init (coalesced in gid order)
  int gbase = simg * GSP;
  for (int i = wave; i < TWORDS; i += 16) {
    u64 rbw = rbm[i];
    if (!rbw) continue;
    if (!((rbw >> lane) & 1)) continue;
    int p = (i << 6) + lane;
    int slot = rcnt[i] - __popcll(rbw) + __popcll(rbw & (((u64)1 << lane) - 1));
    int gid = tin * RCAP + slot;
    sizes[gbase + gid] = par[p] >> 14;
    gparent[gbase + gid] = gid;
  }
  if (t == 0) rootcnt[tile] = rcnt[255];
}

// -------- CCL phase B: seam unites over compact gid space -------------------

__global__ void k_seam_merge(const u64* __restrict__ bm, const int* __restrict__ bound,
                             int* __restrict__ gparent) {
  int gid_t = blockIdx.x * blockDim.x + threadIdx.x;
  int sw = gid_t >> 6;               // 0 .. NSRC*NLVL*NIMG*NSEAM*8-1 = 19199
  if (sw >= NSRC * NLVL * NIMG * NSEAM * 8) return;
  int lane = threadIdx.x & 63;
  int src = sw / (NLVL * NIMG * NSEAM * 8);
  int rem = sw % (NLVL * NIMG * NSEAM * 8);
  int lvl = rem / (NIMG * NSEAM * 8);
  int rem2 = rem % (NIMG * NSEAM * 8);
  int img = rem2 / (NSEAM * 8);
  int rem3 = rem2 % (NSEAM * 8);
  int seam = rem3 >> 3, wc = rem3 & 7;
  int rowb = (seam + 1) * TROWS;     // top row of the lower tile
  const u64* ib = bm + ((size_t)((lvl * NSRC + src) * NIMG + img) << 12);
  int wb = rowb * 8 + wc;
  u64 r0 = ib[wb];
  if (!r0) return;
  u64 up = ib[wb - 8];
  if (!up) return;
  u64 prev = wc ? ib[wb - 1] : 0;
  u64 upprev = wc ? ib[wb - 9] : 0;
  u64 lsr0 = (r0 << 1) | (prev >> 63);
  u64 lsup = (up << 1) | (upprev >> 63);
  u64 need = r0 & up & ~(lsr0 & lsup);
  if ((need >> lane) & 1) {
    int simg = src * NB + lvl * NIMG + img;
    const int* bnd = bound + (size_t)simg * NTILE * 1024;
    int col_a = (wc << 6) + runstart_bit(r0, lane);
    int col_b = (wc << 6) + runstart_bit(up, lane);
    int ga = bnd[(seam + 1) * 1024 + col_a];         // lower tile, row 0
    int gb = bnd[seam * 1024 + 512 + col_b];         // upper tile, row 31
    unite(gparent + (size_t)simg * GSP, ga, gb);
  }
}

// -------- fixup: fold non-global tile-root sizes into their global root ----
// Adds target only global (min-gid) roots -> reads of non-global S race-free.
// Absorbs hist/lcount zeroing.

__global__ __launch_bounds__(256) void k_fixup(const int* __restrict__ rootcnt,
                                               int* __restrict__ gparent,
                                               int* __restrict__ sizes,
                                               int* __restrict__ hist,
                                               int* __restrict__ lcount) {
  int tile = blockIdx.x;             // 2560
  int simg = tile >> 4, tin = tile & 15;
  int t = threadIdx.x;               // 256
  hist[simg * NBIN + tin * 256 + t] = 0;
  if (t == 0 && tin == 0) lcount[simg] = 0;
  int n = rootcnt[tile];
  int* G = gparent + (size_t)simg * GSP;
  int* S = sizes + (size_t)simg * GSP;
  for (int e = t; e < n; e += 256) {
    int gid = tin * RCAP + e;
    int g = gid;
    int q = G[g];
    while (q != g) { g = q; q = G[g]; }
    if (g != gid) atomicAdd(&S[g], S[gid]);
  }
}

// -------- per-tile histogram of global roots (dense coalesced reads) --------

__global__ __launch_bounds__(256) void k_tile_hist(const int* __restrict__ rootcnt,
                                                   const int* __restrict__ gparent,
                                                   const int* __restrict__ sizes,
                                                   int* __restrict__ hist,
                                                   int* __restrict__ lcount,
                                                   int* __restrict__ lsizes) {
  __shared__ int lh[NBIN];           // 16 KB
  int t = threadIdx.x;               // 256
  for (int k = t; k < NBIN; k += 256) lh[k] = 0;
  __syncthreads();
  int tile = blockIdx.x;             // 2560
  int simg = tile >> 4, tin = tile & 15;
  int n = rootcnt[tile];
  const int* G = gparent + (size_t)simg * GSP;
  const int* S = sizes + (size_t)simg * GSP;
  for (int e = t; e < n; e += 256) {
    int gid = tin * RCAP + e;
    if (G[gid] == gid) {             // global root
      int s = S[gid];
      if (s <= NBIN) atomicAdd(&lh[s - 1], 1);
      else {
        int idxl = atomicAdd(&lcount[simg], 1);
        if (idxl < KTOP) lsizes[simg * KTOP + idxl] = s;
      }
    }
  }
  __syncthreads();
  int* gh = hist + simg * NBIN;
  for (int k = t; k < NBIN; k += 256)
    if (lh[k]) atomicAdd(&gh[k], lh[k]);
}

// -------- sorted top-64 per image from the 4096-bin hist + large list -------

__global__ __launch_bounds__(1024) void k_top64(const int* __restrict__ hist,
                                                const int* __restrict__ lcount,
                                                const int* __restrict__ lsizes,
                                                float* __restrict__ top) {
  __shared__ int lh[NBIN];
  __shared__ int sc[1024];
  __shared__ int ls[KTOP];
  int simg = blockIdx.x;             // 0..159
  int t = threadIdx.x;               // 1024
  const int* gh = hist + simg * NBIN;
  for (int k = t; k < NBIN; k += 1024) lh[k] = gh[k];
  int n = lcount[simg];
  if (n > KTOP) n = KTOP;            // n <= 63 mathematically
  if (t < KTOP) ls[t] = (t < n) ? lsizes[simg * KTOP + t] : 0;
  int src = simg / NB;
  int w2 = simg % NB;
  int lvl = w2 >> 4, im = w2 & 15;
  float* tp = top + ((size_t)(src * NLVL + lvl) * NIMG + im) * KTOP;
  if (t < KTOP) tp[t] = 0.f;
  __syncthreads();
  if (t < n) {                       // rank-sort descending large list
    int myv = ls[t], rank = 0;
    for (int j = 0; j < n; ++j) {
      int vj = ls[j];
      rank += (vj > myv) || (vj == myv && j < t);
    }
    tp[rank] = (float)myv;
  }
  int base = NBIN - 4 * (t + 1);     // descending chunks of 4 bins
  int c = lh[base] + lh[base + 1] + lh[base + 2] + lh[base + 3];
  sc[t] = c;
  __syncthreads();
  for (int off = 1; off < 1024; off <<= 1) {   // Hillis-Steele inclusive scan
    int v = (t >= off) ? sc[t - off] : 0;
    __syncthreads();
    sc[t] += v;
    __syncthreads();
  }
  int pos = n + sc[t] - c;           // components ranked before my chunk
  if (pos < KTOP && c > 0) {
    for (int k = 3; k >= 0 && pos < KTOP; --k) {
      int s = base + k + 1;
      int hc = lh[base + k];
      while (hc-- > 0 && pos < KTOP) tp[pos++] = (float)s;
    }
  }
}

// loss[b] = sum over {lvl, c, k} |topP - topT| ; top layout [src][lvl][img][KTOP]
__global__ void k_loss(const float* __restrict__ top, float* __restrict__ out) {
  int b = blockIdx.x;
  int t = threadIdx.x;               // 256
  float acc = 0.f;
  const int TOT = NLVL * CC * KTOP;  // 1280
  for (int e = t; e < TOT; e += 256) {
    int k = e & (KTOP - 1);
    int rest = e >> 6;
    int c = rest & (CC - 1);
    int lvl = rest >> 2;
    int img = b * CC + c;
    size_t iP = ((size_t)(0 * NLVL + lvl) * NIMG + img) * KTOP + k;
    size_t iT = ((size_t)(1 * NLVL + lvl) * NIMG + img) * KTOP + k;
    acc += fabsf(top[iP] - top[iT]);
  }
  __shared__ float r[256];
  r[t] = acc;
  __syncthreads();
  for (int off = 128; off > 0; off >>= 1) {
    if (t < off) r[t] += r[t + off];
    __syncthreads();
  }
  if (t == 0) out[b] = r[0];
}

// ---------------- driver: 8 dispatches total ----------------

extern "C" void kernel_launch(void* const* d_in, const int* in_sizes, int n_in,
                              void* d_out, int out_size, void* d_ws, size_t ws_size,
                              hipStream_t stream) {
  const float* pred = (const float*)d_in[0];
  const int*   tgt  = (const int*)d_in[1];
  float* out = (float*)d_out;

  uint8_t* ws = (uint8_t*)d_ws;
  size_t off = 0;
  u64* bmAll   = (u64*)(ws + off); off += (size_t)NLVL * SLICE * 8;          // 5 MB
  int* bound   = (int*)(ws + off); off += (size_t)NSIMG * NTILE * 1024 * 4;  // 10.5 MB
  int* gparent = (int*)(ws + off); off += (size_t)NSIMG * GSP * 4;           // 84 MB
  int* sizes   = (int*)(ws + off); off += (size_t)NSIMG * GSP * 4;           // 84 MB
  int* rootcnt = (int*)(ws + off); off += (size_t)NSIMG * NTILE * 4;
  int* hist    = (int*)(ws + off); off += (size_t)NSIMG * NBIN * 4;          // 2.6 MB
  int* lcount  = (int*)(ws + off); off += (size_t)NSIMG * 4;
  int* lsizes  = (int*)(ws + off); off += (size_t)NSIMG * KTOP * 4;
  float* top   = (float*)(ws + off); off += (size_t)NSRC * NLVL * NIMG * KTOP * 4;

  // 1) bitmaps: base (lvl 2), then both fused double-morph chains
  k_base_mask_bits<<<(BB * HW) / 256, 256, 0, stream>>>(pred, tgt, bmAll);
  k_morph2<<<512, 256, 0, stream>>>(bmAll);

  // 2) batched CCL, both sources + all levels per dispatch
  k_ccl_tile  <<<NSIMG * NTILE, 1024, 0, stream>>>(bmAll, bound, gparent, sizes, rootcnt);
  k_seam_merge<<<(NSRC * NLVL * NIMG * NSEAM * 8 * 64) / 256, 256, 0, stream>>>(bmAll, bound, gparent);
  k_fixup     <<<NSIMG * NTILE, 256, 0, stream>>>(rootcnt, gparent, sizes, hist, lcount);
  k_tile_hist <<<NSIMG * NTILE, 256, 0, stream>>>(rootcnt, gparent, sizes, hist, lcount, lsizes);
  k_top64     <<<NSIMG, 1024, 0, stream>>>(hist, lcount, lsizes, top);

  // 3) loss
  k_loss<<<BB, 256, 0, stream>>>(top, out);
}

// Round 16
// 156.726 us; speedup vs baseline: 1.0476x; 1.0476x over previous
//
#include <hip/hip_runtime.h>
#include <stdint.h>

typedef unsigned long long u64;
typedef unsigned int u32;

#define BB   4
#define CC   4
#define HHH  512
#define WWW  512
#define HW   (HHH*WWW)        /* 262144 = 2^18 */
#define NIMG (BB*CC)          /* 16 */
#define NSRC 2
#define NLVL 5
#define NB   (NLVL*NIMG)      /* 80 images per src */
#define NSIMG (NSRC*NB)       /* 160 combined batch images */
#define KTOP 64
#define NBIN 4096             /* histogram bins; sizes > NBIN go to the large list (<=63) */
#define WPI  4096             /* 64-bit words per image (512 rows * 8) */
#define SLICE ((size_t)NSRC*NIMG*WPI)  /* words per level slice (131072) */
#define TROWS 32              /* tile = 32 rows x 512 cols */
#define TPX  (TROWS*WWW)      /* 16384 px per tile */
#define TWORDS (TROWS*8)      /* 256 words per tile */
#define NTILE 16              /* tiles per image */
#define NSEAM (NTILE-1)       /* 15 row-seams per image */
#define RCAP 8192             /* max roots per tile (checkerboard bound) */
#define GSP  (NTILE*RCAP)     /* gid space per image (131072) */

// ---------------- union-find over ids (any total order works: only ---------
// connectivity + sizes matter). Convergence test uses ONLY atomic return
// values; path-halving stores write valid ancestors.

__device__ __forceinline__ void unite(int* L, int a, int b) {
  bool done = false;
  do {
    { int p = L[a]; while (p != a) { int gp = L[p]; L[a] = gp; a = gp; p = L[a]; } }
    { int p = L[b]; while (p != b) { int gp = L[p]; L[b] = gp; b = gp; p = L[b]; } }
    if (a < b) {
      int old = atomicMin(&L[b], a);
      done = (old == b);
      b = old;
    } else if (b < a) {
      int old = atomicMin(&L[a], b);
      done = (old == a);
      a = old;
    } else {
      done = true;
    }
  } while (!done);
}

// run start bit (within 64-px segment) for a pixel at bit k of word w
__device__ __forceinline__ int runstart_bit(u64 w, int k) {
  u64 lowz = ~w & ((k == 0) ? 0ull : ((1ull << k) - 1));
  return lowz ? (64 - __clzll(lowz)) : 0;   // highest zero below k, +1
}

// LPT block ordering: heaviest level (base speckle lvl2) first
__device__ __forceinline__ int lvl_of_slot(int s) {
  return s == 0 ? 2 : s == 1 ? 0 : s == 2 ? 1 : s == 3 ? 3 : 4;
}

// 3x3 box morphology of one word given its 8 neighbors packed
__device__ __forceinline__ u64 morph_word(u64 c0, u64 cm, u64 cp, u64 u0, u64 um, u64 up_,
                                          u64 d0, u64 dm, u64 dp, int erode) {
  u64 v, vm, vp;
  if (erode) {
    v = u0 & c0 & d0; vm = um & cm & dm; vp = up_ & cp & dp;
    return v & ((v << 1) | (vm >> 63)) & ((v >> 1) | (vp << 63));
  } else {
    v = u0 | c0 | d0; vm = um | cm | dm; vp = up_ | cp | dp;
    return v | (v << 1) | (vm >> 63) | (v >> 1) | (vp << 63);
  }
}

// ------------- bitmaps: [lvl][src][img][WPI] u64 words, 1 bit/px -----------

__global__ void k_base_mask_bits(const float* __restrict__ pred, const int* __restrict__ tgt,
                                 u64* __restrict__ bm) {
  int i = blockIdx.x * blockDim.x + threadIdx.x;   // over BB*HW
  if (i >= BB * HW) return;
  int b  = i >> 18;
  int hw = i & (HW - 1);
  float p0 = pred[(b * CC + 0) * HW + hw];
  float p1 = pred[(b * CC + 1) * HW + hw];
  float p2 = pred[(b * CC + 2) * HW + hw];
  float p3 = pred[(b * CC + 3) * HW + hw];
  int amax = 0; float best = p0;
  if (p1 > best) { best = p1; amax = 1; }
  if (p2 > best) { best = p2; amax = 2; }
  if (p3 > best) { best = p3; amax = 3; }
  int tg = tgt[i];
  int lane = threadIdx.x & 63;
  u64* bp = bm + 2 * SLICE;                        // lvl2, src0
  u64* bt = bm + 2 * SLICE + (size_t)NIMG * WPI;   // lvl2, src1
#pragma unroll
  for (int c = 0; c < CC; ++c) {
    u64 wp = __ballot(amax == c);
    u64 wt = __ballot(tg == c);
    if (lane == 0) {
      int wi = ((b * CC + c) << 12) + (hw >> 6);
      bp[wi] = wp;
      bt[wi] = wt;
    }
  }
}

// Fused double-morphology, BOTH chains in one dispatch. LDS-tiled, 2-row
// halo; m1 rows outside the image forced to 0.
__global__ void k_morph2(u64* __restrict__ bm) {
  __shared__ u64 a[68 * 8];
  __shared__ u64 bsh[66 * 8];
  int blk = blockIdx.x;              // 512
  int erode = (blk < 256);
  int blk2 = blk & 255;
  int band = blk2 & 7;
  int imgi = blk2 >> 3;              // 0..31 (src*img within level slice)
  int r0 = band * 64;
  const u64* ip = bm + 2 * SLICE + ((size_t)imgi << 12);
  u64* o1 = bm + (erode ? 3 : 1) * SLICE + ((size_t)imgi << 12);
  u64* o2 = bm + (erode ? 4 : 0) * SLICE + ((size_t)imgi << 12);
  int t = threadIdx.x;               // 256
  for (int k = t; k < 68 * 8; k += 256) {
    int rr = r0 - 2 + (k >> 3);
    a[k] = (rr >= 0 && rr < HHH) ? ip[rr * 8 + (k & 7)] : 0;
  }
  __syncthreads();
  for (int k = t; k < 66 * 8; k += 256) {
    int j = k >> 3, wc = k & 7;
    int rr = r0 - 1 + j;
    if (rr < 0 || rr >= HHH) { bsh[k] = 0; continue; }
    int ai = (j + 1) * 8 + wc;
    bsh[k] = morph_word(a[ai], wc ? a[ai - 1] : 0, (wc < 7) ? a[ai + 1] : 0,
                        a[ai - 8], wc ? a[ai - 9] : 0, (wc < 7) ? a[ai - 7] : 0,
                        a[ai + 8], wc ? a[ai + 7] : 0, (wc < 7) ? a[ai + 9] : 0, erode);
  }
  __syncthreads();
  for (int k = t; k < 512; k += 256) {
    int j = k >> 3, wc = k & 7;
    int bi = (j + 1) * 8 + wc;
    o1[(r0 + j) * 8 + wc] = bsh[bi];
    o2[(r0 + j) * 8 + wc] =
        morph_word(bsh[bi], wc ? bsh[bi - 1] : 0, (wc < 7) ? bsh[bi + 1] : 0,
                   bsh[bi - 8], wc ? bsh[bi - 9] : 0, (wc < 7) ? bsh[bi - 7] : 0,
                   bsh[bi + 8], wc ? bsh[bi + 7] : 0, (wc < 7) ? bsh[bi + 9] : 0, erode);
  }
}

// -------- CCL phase A: per-tile UF + sizes in LDS; dense-gid outputs --------
// Round-14 structure (best measured) + both-gate + !rbw emit skip + shfl scan.
// par encoding: low 14 bits = parent pixel idx; bits >=14 = size at roots.

__global__ __launch_bounds__(1024) void k_ccl_tile(const u64* __restrict__ bm,
                                                   int* __restrict__ bound,
                                                   int* __restrict__ gparent,
                                                   int* __restrict__ sizes,
                                                   int* __restrict__ rootcnt) {
  __shared__ int par[TPX];          // 64 KB
  __shared__ u64 w[TWORDS];         // 2 KB
  __shared__ u32 rb32[TWORDS * 2];  // 2 KB root bitmap
  __shared__ int rcnt[256];         // inclusive per-word root counts
  __shared__ int anyfg;
  int t = threadIdx.x;              // 1024
  int idx = blockIdx.x;             // 2560
  int lvl = lvl_of_slot(idx >> 9);
  int rem = idx & 511;
  int src = rem >> 8;
  int img = (rem >> 4) & 15;
  int tin = rem & 15;
  int simg = src * NB + lvl * NIMG + img;   // 0..159
  int tile = simg * NTILE + tin;
  int trow0 = tin * TROWS;
  const u64* ib = bm + ((size_t)((lvl * NSRC + src) * NIMG + img) << 12);
  if (t == 0) anyfg = 0;
  if (t < 512) rb32[t] = 0;
  __syncthreads();
  // fused load + serial head-init
  if (t < TWORDS) {
    u64 wd = ib[trow0 * 8 + t];
    w[t] = wd;
    if (wd) {
      anyfg = 1;                    // benign same-value race
      int segbase = t << 6;
      u64 hm = wd & ~(wd << 1);
      while (hm) {
        int k = __ffsll(hm) - 1; hm &= hm - 1;
        par[segbase + k] = segbase + k;
      }
    }
  }
  __syncthreads();
  if (!anyfg) { if (t == 0) rootcnt[tile] = 0; return; }
  int wave = t >> 6, lane = t & 63;
  // intra-tile unites: one wave per word, one lane per need-bit (LDS atomics)
  for (int i = wave; i < TWORDS; i += 16) {
    u64 r0 = w[i];
    if (!r0) continue;
    int row = i >> 3, wc = i & 7;
    int segbase = i << 6;
    u64 prev = wc ? w[i - 1] : 0;
    if (lane == 0 && (r0 & 1) && (prev >> 63))
      unite(par, segbase, segbase - 64 + runstart_bit(prev, 63));
    if (row) {
      u64 up = w[i - 8];
      u64 both = r0 & up;
      if (both) {
        u64 upprev = wc ? w[i - 9] : 0;
        u64 lsr0 = (r0 << 1) | (prev >> 63);
        u64 lsup = (up << 1) | (upprev >> 63);
        u64 need = both & ~(lsr0 & lsup);
        if ((need >> lane) & 1)
          unite(par, segbase + runstart_bit(r0, lane),
                     segbase - 512 + runstart_bit(up, lane));
      }
    }
  }
  __syncthreads();
  // flatten + size-accumulate + root-bitmap. Masked walk (low 14 bits) is
  // immune to concurrent size atomicAdds (those only target final roots).
  for (int i = wave; i < TWORDS; i += 16) {
    u64 wd = w[i];
    if (!wd) continue;
    u64 hm = wd & ~(wd << 1);
    if ((hm >> lane) & 1) {
      int p = (i << 6) + lane;
      int r = p;
      int q = par[r] & 16383;
      while (q != r) { r = q; q = par[r] & 16383; }
      u64 inv = ~(wd >> lane);
      int len = inv ? (__ffsll(inv) - 1) : (64 - lane);
      atomicAdd(&par[r], len << 14);
      if (r == p) atomicOr(&rb32[p >> 5], 1u << (p & 31));
    }
  }
  __syncthreads();
  // single-wave inclusive scan of per-word root counts (2 barriers not 16)
  if (t < 64) {
    int b4 = t * 4;
    int c0 = __popcll(((u64)rb32[2 * b4 + 1] << 32) | rb32[2 * b4]);
    int c1 = c0 + __popcll(((u64)rb32[2 * b4 + 3] << 32) | rb32[2 * b4 + 2]);
    int c2 = c1 + __popcll(((u64)rb32[2 * b4 + 5] << 32) | rb32[2 * b4 + 4]);
    int c3 = c2 + __popcll(((u64)rb32[2 * b4 + 7] << 32) | rb32[2 * b4 + 6]);
    int sum = c3;
    for (int o = 1; o < 64; o <<= 1) {
      int v = __shfl_up(sum, o);
      if (t >= o) sum += v;
    }
    int excl = sum - c3;
    rcnt[b4] = excl + c0;
    rcnt[b4 + 1] = excl + c1;
    rcnt[b4 + 2] = excl + c2;
    rcnt[b4 + 3] = excl + c3;
  }
  __syncthreads();
  // boundary publish: rows 0 and TROWS-1 (the only seam-unite endpoints)
  if (wave < 16) {
    int ii = wave;
    int i = (ii < 8) ? ii : (240 + ii);            // words 0..7 and 248..255
    u64 wd = w[i];
    if (wd) {
      u64 hm = wd & ~(wd << 1);
      if ((hm >> lane) & 1) {
        int p = (i << 6) + lane;
        int r = p;
        int q = par[r] & 16383;
        while (q != r) { r = q; q = par[r] & 16383; }
        int wi = r >> 6;
        u64 rbw = ((u64)rb32[2 * wi + 1] << 32) | rb32[2 * wi];
        int slot = rcnt[wi] - __popcll(rbw) +
                   __popcll(rbw & (((u64)1 << (r & 63)) - 1));
        bound[(size_t)tile * 1024 + (ii < 8 ? 0 : 512) + ((i & 7) << 6) + lane] =
            tin * RCAP + slot;
      }
    }
  }
  // dense emit of sizes + gparent init (coalesced in gid order)
  int gbase = simg * GSP;
  for (int i = wave; i < TWORDS; i += 16) {
    u64 rbw = ((u64)rb32[2 * i + 1] << 32) | rb32[2 * i];
    if (!rbw) continue;
    if (!((rbw >> lane) & 1)) continue;
    int p = (i << 6) + lane;
    int slot = rcnt[i] - __popcll(rbw) + __popcll(rbw & (((u64)1 << lane) - 1));
    int gid = tin * RCAP + slot;
    sizes[gbase + gid] = par[p] >> 14;
    gparent[gbase + gid] = gid;
  }
  if (t == 0) rootcnt[tile] = rcnt[255];
}

// -------- CCL phase B: seam unites over compact gid space -------------------

__global__ void k_seam_merge(const u64* __restrict__ bm, const int* __restrict__ bound,
                             int* __restrict__ gparent) {
  int gid_t = blockIdx.x * blockDim.x + threadIdx.x;
  int sw = gid_t >> 6;               // 0 .. NSRC*NLVL*NIMG*NSEAM*8-1 = 19199
  if (sw >= NSRC * NLVL * NIMG * NSEAM * 8) return;
  int lane = threadIdx.x & 63;
  int src = sw / (NLVL * NIMG * NSEAM * 8);
  int rem = sw % (NLVL * NIMG * NSEAM * 8);
  int lvl = rem / (NIMG * NSEAM * 8);
  int rem2 = rem % (NIMG * NSEAM * 8);
  int img = rem2 / (NSEAM * 8);
  int rem3 = rem2 % (NSEAM * 8);
  int seam = rem3 >> 3, wc = rem3 & 7;
  int rowb = (seam + 1) * TROWS;     // top row of the lower tile
  const u64* ib = bm + ((size_t)((lvl * NSRC + src) * NIMG + img) << 12);
  int wb = rowb * 8 + wc;
  u64 r0 = ib[wb];
  if (!r0) return;
  u64 up = ib[wb - 8];
  if (!up) return;
  u64 prev = wc ? ib[wb - 1] : 0;
  u64 upprev = wc ? ib[wb - 9] : 0;
  u64 lsr0 = (r0 << 1) | (prev >> 63);
  u64 lsup = (up << 1) | (upprev >> 63);
  u64 need = r0 & up & ~(lsr0 & lsup);
  if ((need >> lane) & 1) {
    int simg = src * NB + lvl * NIMG + img;
    const int* bnd = bound + (size_t)simg * NTILE * 1024;
    int col_a = (wc << 6) + runstart_bit(r0, lane);
    int col_b = (wc << 6) + runstart_bit(up, lane);
    int ga = bnd[(seam + 1) * 1024 + col_a];         // lower tile, row 0
    int gb = bnd[seam * 1024 + 512 + col_b];         // upper tile, row 31
    unite(gparent + (size_t)simg * GSP, ga, gb);
  }
}

// -------- fixup: fold non-global tile-root sizes into their global root ----
// Adds target only global (min-gid) roots -> reads of non-global S race-free.
// Absorbs hist/lcount zeroing.

__global__ __launch_bounds__(256) void k_fixup(const int* __restrict__ rootcnt,
                                               int* __restrict__ gparent,
                                               int* __restrict__ sizes,
                                               int* __restrict__ hist,
                                               int* __restrict__ lcount) {
  int tile = blockIdx.x;             // 2560
  int simg = tile >> 4, tin = tile & 15;
  int t = threadIdx.x;               // 256
  hist[simg * NBIN + tin * 256 + t] = 0;
  if (t == 0 && tin == 0) lcount[simg] = 0;
  int n = rootcnt[tile];
  int* G = gparent + (size_t)simg * GSP;
  int* S = sizes + (size_t)simg * GSP;
  for (int e = t; e < n; e += 256) {
    int gid = tin * RCAP + e;
    int g = gid;
    int q = G[g];
    while (q != g) { g = q; q = G[g]; }
    if (g != gid) atomicAdd(&S[g], S[gid]);
  }
}

// -------- per-tile histogram of global roots (dense coalesced reads) --------

__global__ __launch_bounds__(256) void k_tile_hist(const int* __restrict__ rootcnt,
                                                   const int* __restrict__ gparent,
                                                   const int* __restrict__ sizes,
                                                   int* __restrict__ hist,
                                                   int* __restrict__ lcount,
                                                   int* __restrict__ lsizes) {
  __shared__ int lh[NBIN];           // 16 KB
  int t = threadIdx.x;               // 256
  for (int k = t; k < NBIN; k += 256) lh[k] = 0;
  __syncthreads();
  int tile = blockIdx.x;             // 2560
  int simg = tile >> 4, tin = tile & 15;
  int n = rootcnt[tile];
  const int* G = gparent + (size_t)simg * GSP;
  const int* S = sizes + (size_t)simg * GSP;
  for (int e = t; e < n; e += 256) {
    int gid = tin * RCAP + e;
    if (G[gid] == gid) {             // global root
      int s = S[gid];
      if (s <= NBIN) atomicAdd(&lh[s - 1], 1);
      else {
        int idxl = atomicAdd(&lcount[simg], 1);
        if (idxl < KTOP) lsizes[simg * KTOP + idxl] = s;
      }
    }
  }
  __syncthreads();
  int* gh = hist + simg * NBIN;
  for (int k = t; k < NBIN; k += 256)
    if (lh[k]) atomicAdd(&gh[k], lh[k]);
}

// -------- sorted top-64 per image from the 4096-bin hist + large list -------

__global__ __launch_bounds__(1024) void k_top64(const int* __restrict__ hist,
                                                const int* __restrict__ lcount,
                                                const int* __restrict__ lsizes,
                                                float* __restrict__ top) {
  __shared__ int lh[NBIN];
  __shared__ int sc[1024];
  __shared__ int ls[KTOP];
  int simg = blockIdx.x;             // 0..159
  int t = threadIdx.x;               // 1024
  const int* gh = hist + simg * NBIN;
  for (int k = t; k < NBIN; k += 1024) lh[k] = gh[k];
  int n = lcount[simg];
  if (n > KTOP) n = KTOP;            // n <= 63 mathematically
  if (t < KTOP) ls[t] = (t < n) ? lsizes[simg * KTOP + t] : 0;
  int src = simg / NB;
  int w2 = simg % NB;
  int lvl = w2 >> 4, im = w2 & 15;
  float* tp = top + ((size_t)(src * NLVL + lvl) * NIMG + im) * KTOP;
  if (t < KTOP) tp[t] = 0.f;
  __syncthreads();
  if (t < n) {                       // rank-sort descending large list
    int myv = ls[t], rank = 0;
    for (int j = 0; j < n; ++j) {
      int vj = ls[j];
      rank += (vj > myv) || (vj == myv && j < t);
    }
    tp[rank] = (float)myv;
  }
  int base = NBIN - 4 * (t + 1);     // descending chunks of 4 bins
  int c = lh[base] + lh[base + 1] + lh[base + 2] + lh[base + 3];
  sc[t] = c;
  __syncthreads();
  for (int off = 1; off < 1024; off <<= 1) {   // Hillis-Steele inclusive scan
    int v = (t >= off) ? sc[t - off] : 0;
    __syncthreads();
    sc[t] += v;
    __syncthreads();
  }
  int pos = n + sc[t] - c;           // components ranked before my chunk
  if (pos < KTOP && c > 0) {
    for (int k = 3; k >= 0 && pos < KTOP; --k) {
      int s = base + k + 1;
      int hc = lh[base + k];
      while (hc-- > 0 && pos < KTOP) tp[pos++] = (float)s;
    }
  }
}

// loss[b] = sum over {lvl, c, k} |topP - topT| ; top layout [src][lvl][img][KTOP]
__global__ void k_loss(const float* __restrict__ top, float* __restrict__ out) {
  int b = blockIdx.x;
  int t = threadIdx.x;               // 256
  float acc = 0.f;
  const int TOT = NLVL * CC * KTOP;  // 1280
  for (int e = t; e < TOT; e += 256) {
    int k = e & (KTOP - 1);
    int rest = e >> 6;
    int c = rest & (CC - 1);
    int lvl = rest >> 2;
    int img = b * CC + c;
    size_t iP = ((size_t)(0 * NLVL + lvl) * NIMG + img) * KTOP + k;
    size_t iT = ((size_t)(1 * NLVL + lvl) * NIMG + img) * KTOP + k;
    acc += fabsf(top[iP] - top[iT]);
  }
  __shared__ float r[256];
  r[t] = acc;
  __syncthreads();
  for (int off = 128; off > 0; off >>= 1) {
    if (t < off) r[t] += r[t + off];
    __syncthreads();
  }
  if (t == 0) out[b] = r[0];
}

// ---------------- driver: 8 dispatches total ----------------

extern "C" void kernel_launch(void* const* d_in, const int* in_sizes, int n_in,
                              void* d_out, int out_size, void* d_ws, size_t ws_size,
                              hipStream_t stream) {
  const float* pred = (const float*)d_in[0];
  const int*   tgt  = (const int*)d_in[1];
  float* out = (float*)d_out;

  uint8_t* ws = (uint8_t*)d_ws;
  size_t off = 0;
  u64* bmAll   = (u64*)(ws + off); off += (size_t)NLVL * SLICE * 8;          // 5 MB
  int* bound   = (int*)(ws + off); off += (size_t)NSIMG * NTILE * 1024 * 4;  // 10.5 MB
  int* gparent = (int*)(ws + off); off += (size_t)NSIMG * GSP * 4;           // 84 MB
  int* sizes   = (int*)(ws + off); off += (size_t)NSIMG * GSP * 4;           // 84 MB
  int* rootcnt = (int*)(ws + off); off += (size_t)NSIMG * NTILE * 4;
  int* hist    = (int*)(ws + off); off += (size_t)NSIMG * NBIN * 4;          // 2.6 MB
  int* lcount  = (int*)(ws + off); off += (size_t)NSIMG * 4;
  int* lsizes  = (int*)(ws + off); off += (size_t)NSIMG * KTOP * 4;
  float* top   = (float*)(ws + off); off += (size_t)NSRC * NLVL * NIMG * KTOP * 4;

  // 1) bitmaps: base (lvl 2), then both fused double-morph chains
  k_base_mask_bits<<<(BB * HW) / 256, 256, 0, stream>>>(pred, tgt, bmAll);
  k_morph2<<<512, 256, 0, stream>>>(bmAll);

  // 2) batched CCL, both sources + all levels per dispatch
  k_ccl_tile  <<<NSIMG * NTILE, 1024, 0, stream>>>(bmAll, bound, gparent, sizes, rootcnt);
  k_seam_merge<<<(NSRC * NLVL * NIMG * NSEAM * 8 * 64) / 256, 256, 0, stream>>>(bmAll, bound, gparent);
  k_fixup     <<<NSIMG * NTILE, 256, 0, stream>>>(rootcnt, gparent, sizes, hist, lcount);
  k_tile_hist <<<NSIMG * NTILE, 256, 0, stream>>>(rootcnt, gparent, sizes, hist, lcount, lsizes);
  k_top64     <<<NSIMG, 1024, 0, stream>>>(hist, lcount, lsizes, top);

  // 3) loss
  k_loss<<<BB, 256, 0, stream>>>(top, out);
}